// Round 8
// baseline (216.456 us; speedup 1.0000x reference)
//
#include <hip/hip_runtime.h>
#include <hip/hip_bf16.h>
#include <math.h>

// FraudDetectionNet R17: R16 (cvt_pk fold-proof splitbf, 111.0us, absmax
// 0.0039) + the two LDS-pipe reductions from R12, now EXONERATED:
// R14 (byte-identical R11) failing at the uncompensated signature proved
// R12/R13's failures were environmental (container B's compiler folded the
// old header-based residual to zero), not caused by their restructures.
// With R16's asm-opaque splitbf the compensation cannot die, and live
// compensation bounds any value-identical restructure's effect at ~2
// output-ulp. Changes vs R16 (both value-identical):
//  (a) zcT[n][m], row stride 204 floats (16B-aligned rows; 204%32==12 ->
//      2-way bank alias = free). Per tile ONE ds_read_b128 replaces 4
//      stride-68B ds_read_b32.
//  (b) single deferred reduction: per-image register accumulators
//      (rS0/rV0/rQ0, rS1/rV1/rQ1), tail folded via predicated register
//      adds, ONE 6-value butterfly per wave (was 2 full + tail shuffles
//      + LDS read-modify-writes).
// Numerics: A[k0..15]=psi_hi, A[k16..31]=psi_lo; B1=U_hi replicated across
// K-halves, B2=U_lo replicated; 4 MFMAs/tile reconstruct
// (psi_hi+psi_lo)*(U_hi+U_lo) to ~2^-17 relative. splitbf via
// v_cvt_pk_bf16_f32 inline asm (outputs opaque -> residual subtract can
// never be folded).
// Structure: 1024 blocks (4/CU), 256 thr (4 waves), 8 images/block,
// 2 images/wave, barrier-free main loop in wave-private LDS.

#define NPATCH 196
#define NIMG   8192
#define GIMG   8                // images per block
#define IW     (GIMG / 4)       // images per wave = 2
#define NBLK   (NIMG / GIMG)    // 1024 = 4 blocks/CU on 256 CUs
#define ROWB   80               // 32 bf16 (64B) + 16B pad, 16B-aligned rows
#define ZSTR   204              // zcT row stride in floats

typedef __bf16 bf16x8 __attribute__((ext_vector_type(8)));
typedef float  f32x4  __attribute__((ext_vector_type(4)));

union Frag { bf16x8 v; uint4 u; unsigned us[4]; };

// split a,b into packed bf16 hi words and packed bf16 lo (residual) words.
// v_cvt_pk_bf16_f32: dst = (bf16(src1)<<16) | bf16(src0). Asm outputs are
// opaque -> the residual subtract is fold-proof by construction.
static __device__ inline void splitbf(float a, float b, unsigned& h, unsigned& l) {
    unsigned hp, lp;
    asm("v_cvt_pk_bf16_f32 %0, %1, %2" : "=v"(hp) : "v"(a), "v"(b));
    const float fa = __uint_as_float(hp << 16);
    const float fb = __uint_as_float(hp & 0xFFFF0000u);
    const float ra = a - fa, rb = b - fb;
    asm("v_cvt_pk_bf16_f32 %0, %1, %2" : "=v"(lp) : "v"(ra), "v"(rb));
    h = hp; l = lp;
}

// psi from 4 pixels -> hi (16 bf16) + lo (16 bf16) residuals
static __device__ inline void psi_pack2(float x0, float x1, float x2, float x3,
                                        uint4& h0, uint4& h1, uint4& l0, uint4& l1) {
    float s0, c0, s1, c1, s2, c2, s3, c3;
    __sincosf(0.5f * x0, &s0, &c0);
    __sincosf(0.5f * x1, &s1, &c1);
    __sincosf(0.5f * x2, &s2, &c2);
    __sincosf(0.5f * x3, &s3, &c3);
    const float a01[4] = { c0 * c1, c0 * s1, s0 * c1, s0 * s1 };
    const float a23[4] = { c2 * c3, c2 * s3, s2 * c3, s2 * s3 };
    splitbf(a01[0] * a23[0], a01[0] * a23[1], h0.x, l0.x);
    splitbf(a01[0] * a23[2], a01[0] * a23[3], h0.y, l0.y);
    splitbf(a01[1] * a23[0], a01[1] * a23[1], h0.z, l0.z);
    splitbf(a01[1] * a23[2], a01[1] * a23[3], h0.w, l0.w);
    splitbf(a01[2] * a23[0], a01[2] * a23[1], h1.x, l1.x);
    splitbf(a01[2] * a23[2], a01[2] * a23[3], h1.y, l1.y);
    splitbf(a01[3] * a23[0], a01[3] * a23[1], h1.z, l1.z);
    splitbf(a01[3] * a23[2], a01[3] * a23[3], h1.w, l1.w);
}

__global__ __launch_bounds__(256, 4) void fraud_kernel(
    const float* __restrict__ x,        // (8192, 784)
    const float* __restrict__ w_in,     // (2,2)
    const float* __restrict__ b_in,     // (2,)
    const float* __restrict__ scale_in, // (2,)
    const float* __restrict__ shift_in, // (2,)
    const float* __restrict__ Wc,       // (2,2,2)
    const float* __restrict__ bc,       // (2,2)
    const float* __restrict__ scalec,   // (2,2)
    const float* __restrict__ shiftc,   // (2,2)
    const float* __restrict__ w_out,    // (1,2)
    const float* __restrict__ b_out,    // (1,)
    const float* __restrict__ U_re,     // (16,16)
    const float* __restrict__ U_im,     // (16,16)
    const float* __restrict__ w_cls,    // (785,)
    const float* __restrict__ b_cls,    // (1,)
    float* __restrict__ out)            // (8192,)
{
    __shared__ __align__(16) unsigned char lds[256 * ROWB];  // 20 KB psi rows
    __shared__ __align__(16) float zcT[16 * ZSTR];           // 12.75 KB
    __shared__ float accS[GIMG], accV[GIMG], accQ[GIMG];

    const int tid  = threadIdx.x;
    const int lane = tid & 63;
    const int wv   = tid >> 6;
    const int n16  = lane & 15;
    const int q    = lane >> 4;
    const int img0 = blockIdx.x * GIMG;

    // ---- zcT table: zcT[n][m] = sum_w (1-2*bit_{3-w}(n)) * w_cls[1+4m+w] ----
    for (int i = tid; i < NPATCH * 16; i += 256) {
        const int m = i >> 4, n = i & 15;
        const float* wp = w_cls + 1 + 4 * m;
        const float w0 = wp[0], w1 = wp[1], w2 = wp[2], w3 = wp[3];
        zcT[n * ZSTR + m] = ((n & 8) ? -w0 : w0) + ((n & 4) ? -w1 : w1)
                          + ((n & 2) ? -w2 : w2) + ((n & 1) ? -w3 : w3);
    }

    // ---- B fragments: B[k][n], k = q*8+j.
    //   b1* = U_hi[n][k&15] (replicated across K-halves)
    //   b2* = U_lo[n][k&15] (replicated across K-halves)
    Frag b1re, b1im, b2re, b2im;
    {
        const float* pr = U_re + n16 * 16 + (q & 1) * 8;
        const float* pi = U_im + n16 * 16 + (q & 1) * 8;
        #pragma unroll
        for (int t = 0; t < 4; ++t) {
            splitbf(pr[2 * t], pr[2 * t + 1], b1re.us[t], b2re.us[t]);
            splitbf(pi[2 * t], pi[2 * t + 1], b1im.us[t], b2im.us[t]);
        }
    }

    unsigned char* wbase = lds + wv * 64 * ROWB;
    unsigned* myrow = (unsigned*)(wbase + lane * ROWB);
    const float* zrow = zcT + n16 * ZSTR;

    __syncthreads();   // zcT table ready

    const int imgw0 = img0 + wv * IW;   // this wave's first image

    // ---- prefetch (im=0, c=0) pixels (image imgw0, patch = lane) ----
    float2 ctop, cbot;
    {
        const int p = lane, rr = p / 14, cc = p - rr * 14;
        const float* xp = x + (size_t)imgw0 * 784;
        ctop = *(const float2*)(xp + (2 * rr) * 28 + 2 * cc);
        cbot = *(const float2*)(xp + (2 * rr + 1) * 28 + 2 * cc);
    }

    float rS0 = 0.f, rV0 = 0.f, rQ0 = 0.f;
    float rS1 = 0.f, rV1 = 0.f, rQ1 = 0.f;

    #pragma unroll
    for (int im = 0; im < IW; ++im) {
        #pragma unroll
        for (int c = 0; c < 3; ++c) {
            const float x0 = ctop.x, x1 = ctop.y, x2 = cbot.x, x3 = cbot.y;

            // prefetch next chunk
            if (!(im == IW - 1 && c == 2)) {
                const int nim = (c < 2) ? im : im + 1;
                const int nc  = (c < 2) ? c + 1 : 0;
                const int p = nc * 64 + lane, rr = p / 14, cc = p - rr * 14;
                const float* xp = x + (size_t)(imgw0 + nim) * 784;
                ctop = *(const float2*)(xp + (2 * rr) * 28 + 2 * cc);
                cbot = *(const float2*)(xp + (2 * rr + 1) * 28 + 2 * cc);
            }

            const float sS = x0 + x1 + x2 + x3;
            const float sV = x0 * x0 + x1 * x1 + x2 * x2 + x3 * x3;
            if (im == 0) { rS0 += sS; rV0 += sV; } else { rS1 += sS; rV1 += sV; }

            uint4 h0, h1, l0, l1;
            psi_pack2(x0, x1, x2, x3, h0, h1, l0, l1);
            *(uint4*)(myrow)      = h0;   // k 0..7   psi_hi
            *(uint4*)(myrow + 4)  = h1;   // k 8..15  psi_hi
            *(uint4*)(myrow + 8)  = l0;   // k 16..23 psi_lo
            *(uint4*)(myrow + 12) = l1;   // k 24..31 psi_lo
            asm volatile("s_waitcnt lgkmcnt(0)" ::: "memory");

            float rq = 0.f;
            #pragma unroll
            for (int t = 0; t < 4; ++t) {
                Frag a;   // A[m=n16][k=q*8+j] of this 16-row tile
                a.u = *(const uint4*)(wbase + (t * 16 + n16) * ROWB + q * 16);
                f32x4 cr = {0.f, 0.f, 0.f, 0.f}, ci = {0.f, 0.f, 0.f, 0.f};
                cr = __builtin_amdgcn_mfma_f32_16x16x32_bf16(a.v, b1re.v, cr, 0, 0, 0);
                cr = __builtin_amdgcn_mfma_f32_16x16x32_bf16(a.v, b2re.v, cr, 0, 0, 0);
                ci = __builtin_amdgcn_mfma_f32_16x16x32_bf16(a.v, b1im.v, ci, 0, 0, 0);
                ci = __builtin_amdgcn_mfma_f32_16x16x32_bf16(a.v, b2im.v, ci, 0, 0, 0);
                // one b128 zc read: zcT[n16][c*64 + t*16 + q*4 + j], j=0..3
                const float4 zv = *(const float4*)(zrow + c * 64 + t * 16 + 4 * q);
                rq = fmaf(cr[0] * cr[0] + ci[0] * ci[0], zv.x, rq);
                rq = fmaf(cr[1] * cr[1] + ci[1] * ci[1], zv.y, rq);
                rq = fmaf(cr[2] * cr[2] + ci[2] * ci[2], zv.z, rq);
                rq = fmaf(cr[3] * cr[3] + ci[3] * ci[3], zv.w, rq);
            }
            if (im == 0) rQ0 += rq; else rQ1 += rq;
        }
    }

    // ---- tail chunk: IW images x patches 192..195, lanes 0..4*IW-1 ----
    {
        float tS = 0.f, tV = 0.f;
        if (lane < 4 * IW) {
            const int iml = lane >> 2;            // wave-local image
            const int p   = 192 + (lane & 3);
            const int rr = p / 14, cc = p - rr * 14;
            const float* xp = x + (size_t)(imgw0 + iml) * 784;
            const float2 top = *(const float2*)(xp + (2 * rr) * 28 + 2 * cc);
            const float2 bot = *(const float2*)(xp + (2 * rr + 1) * 28 + 2 * cc);
            const float x0 = top.x, x1 = top.y, x2 = bot.x, x3 = bot.y;
            tS = x0 + x1 + x2 + x3;
            tV = x0 * x0 + x1 * x1 + x2 * x2 + x3 * x3;
            uint4 h0, h1, l0, l1;
            psi_pack2(x0, x1, x2, x3, h0, h1, l0, l1);
            *(uint4*)(myrow)      = h0;   // row l holds (img l>>2, patch 192+(l&3))
            *(uint4*)(myrow + 4)  = h1;
            *(uint4*)(myrow + 8)  = l0;
            *(uint4*)(myrow + 12) = l1;
        }
        asm volatile("s_waitcnt lgkmcnt(0)" ::: "memory");

        float tq = 0.f;
        {
            Frag a;   // tile 0 only: rows 0..15 (rows >= 4*IW stale-but-finite)
            a.u = *(const uint4*)(wbase + n16 * ROWB + q * 16);
            f32x4 cr = {0.f, 0.f, 0.f, 0.f}, ci = {0.f, 0.f, 0.f, 0.f};
            cr = __builtin_amdgcn_mfma_f32_16x16x32_bf16(a.v, b1re.v, cr, 0, 0, 0);
            cr = __builtin_amdgcn_mfma_f32_16x16x32_bf16(a.v, b2re.v, cr, 0, 0, 0);
            ci = __builtin_amdgcn_mfma_f32_16x16x32_bf16(a.v, b1im.v, ci, 0, 0, 0);
            ci = __builtin_amdgcn_mfma_f32_16x16x32_bf16(a.v, b2im.v, ci, 0, 0, 0);
            // lane (q,n16) holds prob[m=q*4+j][n16]: image q (valid q<IW),
            // patch 192+j.  zcT[n16][192+j]: q-independent addr (broadcast).
            const float4 zt = *(const float4*)(zrow + 192);
            tq = fmaf(cr[0] * cr[0] + ci[0] * ci[0], zt.x, tq);
            tq = fmaf(cr[1] * cr[1] + ci[1] * ci[1], zt.y, tq);
            tq = fmaf(cr[2] * cr[2] + ci[2] * ci[2], zt.z, tq);
            tq = fmaf(cr[3] * cr[3] + ci[3] * ci[3], zt.w, tq);
        }

        // fold tail into per-image register accumulators (pre-reduction):
        // pixel sums live in lanes 0..7 (image = lane>>2), quantum partials
        // in all lanes (image = q; only q<IW valid). The single butterfly
        // below sums every lane's contribution.
        if (lane < 4)      { rS0 += tS; rV0 += tV; }
        else if (lane < 8) { rS1 += tS; rV1 += tV; }
        if (q == 0)        rQ0 += tq;
        else if (q == 1)   rQ1 += tq;
    }

    // ---- ONE 6-value butterfly reduction per wave ----
    #pragma unroll
    for (int off = 1; off < 64; off <<= 1) {
        rS0 += __shfl_xor(rS0, off, 64);
        rV0 += __shfl_xor(rV0, off, 64);
        rQ0 += __shfl_xor(rQ0, off, 64);
        rS1 += __shfl_xor(rS1, off, 64);
        rV1 += __shfl_xor(rV1, off, 64);
        rQ1 += __shfl_xor(rQ1, off, 64);
    }
    if (lane == 0) {
        accS[wv * IW + 0] = rS0;  accV[wv * IW + 0] = rV0;  accQ[wv * IW + 0] = rQ0;
        accS[wv * IW + 1] = rS1;  accV[wv * IW + 1] = rV1;  accQ[wv * IW + 1] = rQ1;
    }
    __syncthreads();

    // ---- final: GIMG threads, one image each ----
    if (tid < GIMG) {
        const float S  = accS[tid];
        const float SS = accV[tid];
        const float QS = accQ[tid];

        const float mean = S * (1.f / 784.f);
        float var = (SS - S * S * (1.f / 784.f)) * (1.f / 783.f);  // ddof=1
        var = fmaxf(var, 0.f);
        const float stdv = sqrtf(var);

        float h0 = mean, h1 = stdv;
        {
            const float t0 = tanhf(h0 * w_in[0] + h1 * w_in[1] + b_in[0]);
            const float t1 = tanhf(h0 * w_in[2] + h1 * w_in[3] + b_in[1]);
            h0 = t0 * scale_in[0] + shift_in[0];
            h1 = t1 * scale_in[1] + shift_in[1];
        }
        #pragma unroll
        for (int l = 0; l < 2; ++l) {
            const float t0 = tanhf(h0 * Wc[l * 4 + 0] + h1 * Wc[l * 4 + 1] + bc[l * 2 + 0]);
            const float t1 = tanhf(h0 * Wc[l * 4 + 2] + h1 * Wc[l * 4 + 3] + bc[l * 2 + 1]);
            h0 = t0 * scalec[l * 2 + 0] + shiftc[l * 2 + 0];
            h1 = t1 * scalec[l * 2 + 1] + shiftc[l * 2 + 1];
        }
        const float cls   = h0 * w_out[0] + h1 * w_out[1] + b_out[0];
        const float logit = b_cls[0] + w_cls[0] * cls + QS;
        out[img0 + tid] = 1.f / (1.f + __expf(-logit));
    }
}

extern "C" void kernel_launch(void* const* d_in, const int* in_sizes, int n_in,
                              void* d_out, int out_size, void* d_ws, size_t ws_size,
                              hipStream_t stream) {
    const float* x        = (const float*)d_in[0];
    const float* w_in     = (const float*)d_in[1];
    const float* b_in     = (const float*)d_in[2];
    const float* scale_in = (const float*)d_in[3];
    const float* shift_in = (const float*)d_in[4];
    const float* Wc       = (const float*)d_in[5];
    const float* bc       = (const float*)d_in[6];
    const float* scalec   = (const float*)d_in[7];
    const float* shiftc   = (const float*)d_in[8];
    const float* w_out    = (const float*)d_in[9];
    const float* b_out    = (const float*)d_in[10];
    const float* U_re     = (const float*)d_in[11];
    const float* U_im     = (const float*)d_in[12];
    const float* w_cls    = (const float*)d_in[13];
    const float* b_cls    = (const float*)d_in[14];
    float* out = (float*)d_out;

    fraud_kernel<<<NBLK, 256, 0, stream>>>(x, w_in, b_in, scale_in, shift_in,
                                           Wc, bc, scalec, shiftc, w_out, b_out,
                                           U_re, U_im, w_cls, b_cls, out);
}

// Round 9
// 110.453 us; speedup vs baseline: 1.9597x; 1.9597x over previous
//
#include <hip/hip_runtime.h>
#include <hip/hip_bf16.h>
#include <math.h>

// FraudDetectionNet R18: R16 VERBATIM LOOP (proven 111.0us in container B)
// + ONLY the zcT transpose (change (a)).
// R17 post-mortem: adding the deferred-reduction restructure (b) required a
// fully-unrolled 6-chunk body; 6 live accumulators + 96 hoistable cvt_pk asm
// statements blew the 128-VGPR cap and SPILLED (counters: WRITE_SIZE 233MB,
// FETCH 134MB vs 25.7MB true footprint; fraud_kernel 133us/dispatch).
// R16's unroll-3 idx loop with per-image butterfly+reset keeps live ranges
// short -> no spill. (b) is abandoned; its ~1us value is not worth the
// register-pressure hazard.
// Change (a), kept: zcT[n][m], row stride 204 floats (16B-aligned rows;
// 204%32==12 -> 2-way alias on b128 reads, ~free). Per tile ONE
// ds_read_b128 replaces 4 stride-68B ds_read_b32 (16 -> 4 LDS ops/chunk);
// tail reads one q-broadcast float4.
// Numerics: A[k0..15]=psi_hi, A[k16..31]=psi_lo; B1=U_hi replicated across
// K-halves, B2=U_lo replicated; 4 MFMAs/tile reconstruct
// (psi_hi+psi_lo)*(U_hi+U_lo) to ~2^-17 relative. splitbf via
// v_cvt_pk_bf16_f32 inline asm (outputs opaque -> residual subtract can
// never be folded -- container B's compiler killed the header-based
// residual; see R14/R15 history).
// Structure: 1024 blocks (4/CU), 256 thr (4 waves), 8 images/block,
// 2 images/wave, barrier-free main loop in wave-private LDS.

#define NPATCH 196
#define NIMG   8192
#define GIMG   8                // images per block
#define IW     (GIMG / 4)       // images per wave = 2
#define NCH    (IW * 3)         // main chunks per wave = 6
#define NBLK   (NIMG / GIMG)    // 1024 = 4 blocks/CU on 256 CUs
#define ROWB   80               // 32 bf16 (64B) + 16B pad, 16B-aligned rows
#define ZSTR   204              // zcT row stride in floats

typedef __bf16 bf16x8 __attribute__((ext_vector_type(8)));
typedef float  f32x4  __attribute__((ext_vector_type(4)));

union Frag { bf16x8 v; uint4 u; unsigned us[4]; };

// split a,b into packed bf16 hi words and packed bf16 lo (residual) words.
// v_cvt_pk_bf16_f32: dst = (bf16(src1)<<16) | bf16(src0). Asm outputs are
// opaque -> the residual subtract is fold-proof by construction.
static __device__ inline void splitbf(float a, float b, unsigned& h, unsigned& l) {
    unsigned hp, lp;
    asm("v_cvt_pk_bf16_f32 %0, %1, %2" : "=v"(hp) : "v"(a), "v"(b));
    const float fa = __uint_as_float(hp << 16);
    const float fb = __uint_as_float(hp & 0xFFFF0000u);
    const float ra = a - fa, rb = b - fb;
    asm("v_cvt_pk_bf16_f32 %0, %1, %2" : "=v"(lp) : "v"(ra), "v"(rb));
    h = hp; l = lp;
}

// psi from 4 pixels -> hi (16 bf16) + lo (16 bf16) residuals
static __device__ inline void psi_pack2(float x0, float x1, float x2, float x3,
                                        uint4& h0, uint4& h1, uint4& l0, uint4& l1) {
    float s0, c0, s1, c1, s2, c2, s3, c3;
    __sincosf(0.5f * x0, &s0, &c0);
    __sincosf(0.5f * x1, &s1, &c1);
    __sincosf(0.5f * x2, &s2, &c2);
    __sincosf(0.5f * x3, &s3, &c3);
    const float a01[4] = { c0 * c1, c0 * s1, s0 * c1, s0 * s1 };
    const float a23[4] = { c2 * c3, c2 * s3, s2 * c3, s2 * s3 };
    splitbf(a01[0] * a23[0], a01[0] * a23[1], h0.x, l0.x);
    splitbf(a01[0] * a23[2], a01[0] * a23[3], h0.y, l0.y);
    splitbf(a01[1] * a23[0], a01[1] * a23[1], h0.z, l0.z);
    splitbf(a01[1] * a23[2], a01[1] * a23[3], h0.w, l0.w);
    splitbf(a01[2] * a23[0], a01[2] * a23[1], h1.x, l1.x);
    splitbf(a01[2] * a23[2], a01[2] * a23[3], h1.y, l1.y);
    splitbf(a01[3] * a23[0], a01[3] * a23[1], h1.z, l1.z);
    splitbf(a01[3] * a23[2], a01[3] * a23[3], h1.w, l1.w);
}

__global__ __launch_bounds__(256, 4) void fraud_kernel(
    const float* __restrict__ x,        // (8192, 784)
    const float* __restrict__ w_in,     // (2,2)
    const float* __restrict__ b_in,     // (2,)
    const float* __restrict__ scale_in, // (2,)
    const float* __restrict__ shift_in, // (2,)
    const float* __restrict__ Wc,       // (2,2,2)
    const float* __restrict__ bc,       // (2,2)
    const float* __restrict__ scalec,   // (2,2)
    const float* __restrict__ shiftc,   // (2,2)
    const float* __restrict__ w_out,    // (1,2)
    const float* __restrict__ b_out,    // (1,)
    const float* __restrict__ U_re,     // (16,16)
    const float* __restrict__ U_im,     // (16,16)
    const float* __restrict__ w_cls,    // (785,)
    const float* __restrict__ b_cls,    // (1,)
    float* __restrict__ out)            // (8192,)
{
    __shared__ __align__(16) unsigned char lds[256 * ROWB];  // 20 KB psi rows
    __shared__ __align__(16) float zcT[16 * ZSTR];           // 12.75 KB
    __shared__ float accS[GIMG], accV[GIMG], accQ[GIMG];

    const int tid  = threadIdx.x;
    const int lane = tid & 63;
    const int wv   = tid >> 6;
    const int n16  = lane & 15;
    const int q    = lane >> 4;
    const int img0 = blockIdx.x * GIMG;

    // ---- zcT table: zcT[n][m] = sum_w (1-2*bit_{3-w}(n)) * w_cls[1+4m+w] ----
    for (int i = tid; i < NPATCH * 16; i += 256) {
        const int m = i >> 4, n = i & 15;
        const float* wp = w_cls + 1 + 4 * m;
        const float w0 = wp[0], w1 = wp[1], w2 = wp[2], w3 = wp[3];
        zcT[n * ZSTR + m] = ((n & 8) ? -w0 : w0) + ((n & 4) ? -w1 : w1)
                          + ((n & 2) ? -w2 : w2) + ((n & 1) ? -w3 : w3);
    }

    // ---- B fragments: B[k][n], k = q*8+j.
    //   b1* = U_hi[n][k&15] (replicated across K-halves)
    //   b2* = U_lo[n][k&15] (replicated across K-halves)
    Frag b1re, b1im, b2re, b2im;
    {
        const float* pr = U_re + n16 * 16 + (q & 1) * 8;
        const float* pi = U_im + n16 * 16 + (q & 1) * 8;
        #pragma unroll
        for (int t = 0; t < 4; ++t) {
            splitbf(pr[2 * t], pr[2 * t + 1], b1re.us[t], b2re.us[t]);
            splitbf(pi[2 * t], pi[2 * t + 1], b1im.us[t], b2im.us[t]);
        }
    }

    unsigned char* wbase = lds + wv * 64 * ROWB;
    unsigned* myrow = (unsigned*)(wbase + lane * ROWB);
    const float* zrow = zcT + n16 * ZSTR;

    __syncthreads();   // zcT table ready

    const int imgw0 = img0 + wv * IW;   // this wave's first image

    // ---- prefetch chunk idx=0 pixels (image imgw0, patch = lane) ----
    float2 ctop, cbot;
    {
        const int p = lane, rr = p / 14, cc = p - rr * 14;
        const float* xp = x + (size_t)imgw0 * 784;
        ctop = *(const float2*)(xp + (2 * rr) * 28 + 2 * cc);
        cbot = *(const float2*)(xp + (2 * rr + 1) * 28 + 2 * cc);
    }

    float rS = 0.f, rV = 0.f, rQ = 0.f;

    #pragma unroll 3
    for (int idx = 0; idx < NCH; ++idx) {
        const int im = idx / 3;            // wave-local image 0..IW-1
        const int c  = idx - im * 3;       // chunk 0..2
        const float x0 = ctop.x, x1 = ctop.y, x2 = cbot.x, x3 = cbot.y;

        // prefetch next chunk
        if (idx < NCH - 1) {
            const int nidx = idx + 1;
            const int nim = nidx / 3, nc = nidx - nim * 3;
            const int p = nc * 64 + lane, rr = p / 14, cc = p - rr * 14;
            const float* xp = x + (size_t)(imgw0 + nim) * 784;
            ctop = *(const float2*)(xp + (2 * rr) * 28 + 2 * cc);
            cbot = *(const float2*)(xp + (2 * rr + 1) * 28 + 2 * cc);
        }

        rS += x0 + x1 + x2 + x3;
        rV += x0 * x0 + x1 * x1 + x2 * x2 + x3 * x3;

        uint4 h0, h1, l0, l1;
        psi_pack2(x0, x1, x2, x3, h0, h1, l0, l1);
        *(uint4*)(myrow)      = h0;   // k 0..7   psi_hi
        *(uint4*)(myrow + 4)  = h1;   // k 8..15  psi_hi
        *(uint4*)(myrow + 8)  = l0;   // k 16..23 psi_lo
        *(uint4*)(myrow + 12) = l1;   // k 24..31 psi_lo
        asm volatile("s_waitcnt lgkmcnt(0)" ::: "memory");

        #pragma unroll
        for (int t = 0; t < 4; ++t) {
            Frag a;   // A[m=n16][k=q*8+j] of this 16-row tile
            a.u = *(const uint4*)(wbase + (t * 16 + n16) * ROWB + q * 16);
            f32x4 cr = {0.f, 0.f, 0.f, 0.f}, ci = {0.f, 0.f, 0.f, 0.f};
            cr = __builtin_amdgcn_mfma_f32_16x16x32_bf16(a.v, b1re.v, cr, 0, 0, 0);
            cr = __builtin_amdgcn_mfma_f32_16x16x32_bf16(a.v, b2re.v, cr, 0, 0, 0);
            ci = __builtin_amdgcn_mfma_f32_16x16x32_bf16(a.v, b1im.v, ci, 0, 0, 0);
            ci = __builtin_amdgcn_mfma_f32_16x16x32_bf16(a.v, b2im.v, ci, 0, 0, 0);
            // one b128 zc read: zcT[n16][c*64 + t*16 + q*4 + j], j=0..3
            const float4 zv = *(const float4*)(zrow + c * 64 + t * 16 + 4 * q);
            rQ = fmaf(cr[0] * cr[0] + ci[0] * ci[0], zv.x, rQ);
            rQ = fmaf(cr[1] * cr[1] + ci[1] * ci[1], zv.y, rQ);
            rQ = fmaf(cr[2] * cr[2] + ci[2] * ci[2], zv.z, rQ);
            rQ = fmaf(cr[3] * cr[3] + ci[3] * ci[3], zv.w, rQ);
        }

        if (c == 2) {   // image finished: reduce & store
            #pragma unroll
            for (int off = 1; off < 64; off <<= 1) {
                rS += __shfl_xor(rS, off, 64);
                rV += __shfl_xor(rV, off, 64);
                rQ += __shfl_xor(rQ, off, 64);
            }
            if (lane == 0) {
                accS[wv * IW + im] = rS;
                accV[wv * IW + im] = rV;
                accQ[wv * IW + im] = rQ;
            }
            rS = 0.f; rV = 0.f; rQ = 0.f;
        }
    }

    // ---- tail chunk: IW images x patches 192..195, lanes 0..4*IW-1 ----
    float tS = 0.f, tV = 0.f;
    if (lane < 4 * IW) {
        const int iml = lane >> 2;            // wave-local image
        const int p   = 192 + (lane & 3);
        const int rr = p / 14, cc = p - rr * 14;
        const float* xp = x + (size_t)(imgw0 + iml) * 784;
        const float2 top = *(const float2*)(xp + (2 * rr) * 28 + 2 * cc);
        const float2 bot = *(const float2*)(xp + (2 * rr + 1) * 28 + 2 * cc);
        const float x0 = top.x, x1 = top.y, x2 = bot.x, x3 = bot.y;
        tS = x0 + x1 + x2 + x3;
        tV = x0 * x0 + x1 * x1 + x2 * x2 + x3 * x3;
        uint4 h0, h1, l0, l1;
        psi_pack2(x0, x1, x2, x3, h0, h1, l0, l1);
        *(uint4*)(myrow)      = h0;   // row l holds (img l>>2, patch 192+(l&3))
        *(uint4*)(myrow + 4)  = h1;
        *(uint4*)(myrow + 8)  = l0;
        *(uint4*)(myrow + 12) = l1;
    }
    asm volatile("s_waitcnt lgkmcnt(0)" ::: "memory");

    float tQ = 0.f;
    {
        Frag a;   // tile 0 only: rows 0..15 (rows >= 4*IW stale-but-finite)
        a.u = *(const uint4*)(wbase + n16 * ROWB + q * 16);
        f32x4 cr = {0.f, 0.f, 0.f, 0.f}, ci = {0.f, 0.f, 0.f, 0.f};
        cr = __builtin_amdgcn_mfma_f32_16x16x32_bf16(a.v, b1re.v, cr, 0, 0, 0);
        cr = __builtin_amdgcn_mfma_f32_16x16x32_bf16(a.v, b2re.v, cr, 0, 0, 0);
        ci = __builtin_amdgcn_mfma_f32_16x16x32_bf16(a.v, b1im.v, ci, 0, 0, 0);
        ci = __builtin_amdgcn_mfma_f32_16x16x32_bf16(a.v, b2im.v, ci, 0, 0, 0);
        // lane (q,n16) holds prob[m=q*4+j][n16]: image q (valid q<IW),
        // patch 192+j.  zcT[n16][192+j]: q-independent addr (broadcast).
        const float4 zt = *(const float4*)(zrow + 192);
        tQ = fmaf(cr[0] * cr[0] + ci[0] * ci[0], zt.x, tQ);
        tQ = fmaf(cr[1] * cr[1] + ci[1] * ci[1], zt.y, tQ);
        tQ = fmaf(cr[2] * cr[2] + ci[2] * ci[2], zt.z, tQ);
        tQ = fmaf(cr[3] * cr[3] + ci[3] * ci[3], zt.w, tQ);
    }
    // pixel sums: reduce within 4-lane groups (image = lane>>2 for lanes<4*IW)
    tS += __shfl_xor(tS, 1, 64);  tS += __shfl_xor(tS, 2, 64);
    tV += __shfl_xor(tV, 1, 64);  tV += __shfl_xor(tV, 2, 64);
    // quantum: reduce within 16-lane groups (image = q)
    tQ += __shfl_xor(tQ, 1, 64);  tQ += __shfl_xor(tQ, 2, 64);
    tQ += __shfl_xor(tQ, 4, 64);  tQ += __shfl_xor(tQ, 8, 64);

    if (lane < 4 * IW && (lane & 3) == 0) {   // one lane per image
        const int iml = lane >> 2;
        accS[wv * IW + iml] += tS;
        accV[wv * IW + iml] += tV;
    }
    if (n16 == 0 && q < IW) {                  // lane group q -> image q
        accQ[wv * IW + q] += tQ;
    }
    __syncthreads();

    // ---- final: GIMG threads, one image each ----
    if (tid < GIMG) {
        const float S  = accS[tid];
        const float SS = accV[tid];
        const float QS = accQ[tid];

        const float mean = S * (1.f / 784.f);
        float var = (SS - S * S * (1.f / 784.f)) * (1.f / 783.f);  // ddof=1
        var = fmaxf(var, 0.f);
        const float stdv = sqrtf(var);

        float h0 = mean, h1 = stdv;
        {
            const float t0 = tanhf(h0 * w_in[0] + h1 * w_in[1] + b_in[0]);
            const float t1 = tanhf(h0 * w_in[2] + h1 * w_in[3] + b_in[1]);
            h0 = t0 * scale_in[0] + shift_in[0];
            h1 = t1 * scale_in[1] + shift_in[1];
        }
        #pragma unroll
        for (int l = 0; l < 2; ++l) {
            const float t0 = tanhf(h0 * Wc[l * 4 + 0] + h1 * Wc[l * 4 + 1] + bc[l * 2 + 0]);
            const float t1 = tanhf(h0 * Wc[l * 4 + 2] + h1 * Wc[l * 4 + 3] + bc[l * 2 + 1]);
            h0 = t0 * scalec[l * 2 + 0] + shiftc[l * 2 + 0];
            h1 = t1 * scalec[l * 2 + 1] + shiftc[l * 2 + 1];
        }
        const float cls   = h0 * w_out[0] + h1 * w_out[1] + b_out[0];
        const float logit = b_cls[0] + w_cls[0] * cls + QS;
        out[img0 + tid] = 1.f / (1.f + __expf(-logit));
    }
}

extern "C" void kernel_launch(void* const* d_in, const int* in_sizes, int n_in,
                              void* d_out, int out_size, void* d_ws, size_t ws_size,
                              hipStream_t stream) {
    const float* x        = (const float*)d_in[0];
    const float* w_in     = (const float*)d_in[1];
    const float* b_in     = (const float*)d_in[2];
    const float* scale_in = (const float*)d_in[3];
    const float* shift_in = (const float*)d_in[4];
    const float* Wc       = (const float*)d_in[5];
    const float* bc       = (const float*)d_in[6];
    const float* scalec   = (const float*)d_in[7];
    const float* shiftc   = (const float*)d_in[8];
    const float* w_out    = (const float*)d_in[9];
    const float* b_out    = (const float*)d_in[10];
    const float* U_re     = (const float*)d_in[11];
    const float* U_im     = (const float*)d_in[12];
    const float* w_cls    = (const float*)d_in[13];
    const float* b_cls    = (const float*)d_in[14];
    float* out = (float*)d_out;

    fraud_kernel<<<NBLK, 256, 0, stream>>>(x, w_in, b_in, scale_in, shift_in,
                                           Wc, bc, scalec, shiftc, w_out, b_out,
                                           U_re, U_im, w_cls, b_cls, out);
}